// Round 3
// baseline (722.620 us; speedup 1.0000x reference)
//
#include <hip/hip_runtime.h>

#define N_NODES 2048
#define C_CH    128
#define N_SPEC  10

// --- symmetric-reduced coefficient page per (species, channel) ---------------
// Layout: main[219][8] (monomial-major, i=0..7) | tail[219] (i==8), pad to 2048.
// Monomial order: m=0..164 sorted triples a<=b<=j (lex), 165..209 sorted pairs
// a<=b (lex), 210..218 singles a.
#define PAGE2   2048
#define NMONO   219
#define MAIN_F  1752          // 219*8

// --- symmetrized-U region layout (floats, within d_ws at US_OFF_B) ----------
#define US3_0   0        // 165*10*1 = 1650
#define US3_1   1650     // 165*11*3 = 5445
#define US3_2   7095     // 165*13*5 = 10725
#define US2_0   17820    // 45*3*1   = 135
#define US2_1   17955    // 45*2*3   = 270
#define US2_2   18225    // 45*3*5   = 675
#define US_TOT  18900

#define US_OFF_B  (128 * 1024)
#define CG_OFF_B  (256 * 1024)
#define CG_BYTES  ((size_t)N_SPEC * C_CH * PAGE2 * 4)

// ---------------------------------------------------------------------------
// Kernel 1: bucket nodes by species. Single block; LDS atomics for positions.
// ---------------------------------------------------------------------------
__global__ __launch_bounds__(1024) void bucket_kernel(const int* __restrict__ index,
                                                      int* __restrict__ counts,
                                                      int* __restrict__ lists) {
    __shared__ int sc[N_SPEC];
    const int tid = threadIdx.x;
    if (tid < N_SPEC) sc[tid] = 0;
    __syncthreads();
    for (int n = tid; n < N_NODES; n += blockDim.x) {
        int s = index[n];
        int pos = atomicAdd(&sc[s], 1);
        lists[s * N_NODES + pos] = n;
    }
    __syncthreads();
    if (tid < N_SPEC) counts[tid] = sc[tid];
}

struct Params {
    const float* U3[3]; const float* W3[3];
    const float* U2[3]; const float* W2[3];
    const float* U1[3]; const float* W1[3];
};

// ---------------------------------------------------------------------------
// Kernel 2: symmetrize U over permutation groups of the feature indices.
// (verified in round 2, unchanged)
// ---------------------------------------------------------------------------
__global__ __launch_bounds__(256) void usym_kernel(Params p, float* __restrict__ Us) {
    const int t = blockIdx.x * 256 + threadIdx.x;
    if (t >= US_TOT) return;

    bool is3; int mul, ird, r; const float* u;
    if (t < US3_1)       { is3 = true;  mul = 10; ird = 1; r = t;          u = p.U3[0]; }
    else if (t < US3_2)  { is3 = true;  mul = 11; ird = 3; r = t - US3_1;  u = p.U3[1]; }
    else if (t < US2_0)  { is3 = true;  mul = 13; ird = 5; r = t - US3_2;  u = p.U3[2]; }
    else if (t < US2_1)  { is3 = false; mul = 3;  ird = 1; r = t - US2_0;  u = p.U2[0]; }
    else if (t < US2_2)  { is3 = false; mul = 2;  ird = 3; r = t - US2_1;  u = p.U2[1]; }
    else                 { is3 = false; mul = 3;  ird = 5; r = t - US2_2;  u = p.U2[2]; }

    const int mi  = mul * ird;
    const int n   = r / mi;
    const int rem = r - n * mi;           // k*ird + il

    float acc = 0.f;
    if (is3) {
        int aa = 0, bb = 0, jj = 0, ctr = 0;
        for (int a2 = 0; a2 < 9; ++a2)
            for (int b2 = a2; b2 < 9; ++b2)
                for (int j2 = b2; j2 < 9; ++j2) {
                    if (ctr == n) { aa = a2; bb = b2; jj = j2; }
                    ++ctr;
                }
        int L[6];
        L[0] = (aa * 9 + bb) * 9 + jj; L[1] = (aa * 9 + jj) * 9 + bb;
        L[2] = (bb * 9 + aa) * 9 + jj; L[3] = (bb * 9 + jj) * 9 + aa;
        L[4] = (jj * 9 + aa) * 9 + bb; L[5] = (jj * 9 + bb) * 9 + aa;
        for (int m = 0; m < 6; ++m) {
            bool dup = false;
            for (int mm = 0; mm < m; ++mm) dup = dup || (L[mm] == L[m]);
            if (!dup) acc += u[L[m] * mi + rem];
        }
    } else {
        int aa = 0, bb = 0, ctr = 0;
        for (int a2 = 0; a2 < 9; ++a2)
            for (int b2 = a2; b2 < 9; ++b2) {
                if (ctr == n) { aa = a2; bb = b2; }
                ++ctr;
            }
        acc = u[(aa * 9 + bb) * mi + rem];
        if (aa != bb) acc += u[(bb * 9 + aa) * mi + rem];
    }
    Us[t] = acc;
}

// ---------------------------------------------------------------------------
// Kernel 3: build pages.  lane = channel; W slice in registers (compile-time
// MUL so wv[] stays in VGPRs); Us chunk staged in LDS, broadcast-read.
// Grid: 10 species x 30 (region,chunk) = 300 blocks x 128 threads.
// ---------------------------------------------------------------------------
template <int MUL, int IRD, int IOFF, int MOFF>
__device__ inline void coefRegion(const float* __restrict__ src,   // rows*MUL*IRD
                                  const float* __restrict__ W,     // [spec][MUL][C]
                                  int s, int row0, int rows,
                                  float* __restrict__ Cg, float* __restrict__ sU) {
    const int c   = threadIdx.x;
    float wv[MUL];
#pragma unroll
    for (int k = 0; k < MUL; ++k) wv[k] = W[(s * MUL + k) * C_CH + c];

    const int nfl = rows * MUL * IRD;
    const float* sp = src + row0 * MUL * IRD;
    for (int f = c; f < nfl; f += 128) sU[f] = sp[f];
    __syncthreads();

    const size_t pb = (size_t)(s * C_CH + c) * PAGE2;
    for (int rr = 0; rr < rows; ++rr) {
        const int m = MOFF + row0 + rr;
#pragma unroll
        for (int il = 0; il < IRD; ++il) {
            float a = 0.f;
#pragma unroll
            for (int k = 0; k < MUL; ++k)
                a += sU[(rr * MUL + k) * IRD + il] * wv[k];
            const int i = IOFF + il;
            Cg[pb + (i < 8 ? m * 8 + i : MAIN_F + m)] = a;
        }
    }
}

__global__ __launch_bounds__(128) void coef_kernel(Params p, const float* __restrict__ Us,
                                                   float* __restrict__ Cg) {
    __shared__ float sU[1560];   // max chunk: 24 rows * 13 * 5
    const int s = blockIdx.x / 30;
    const int t = blockIdx.x % 30;

    if (t < 7) {            // (3,0e) rows 165
        int rel = t, row0 = rel * 24, rows = (rel == 6) ? 21 : 24;
        coefRegion<10, 1, 0, 0>(Us + US3_0, p.W3[0], s, row0, rows, Cg, sU);
    } else if (t < 14) {    // (3,1o)
        int rel = t - 7, row0 = rel * 24, rows = (rel == 6) ? 21 : 24;
        coefRegion<11, 3, 1, 0>(Us + US3_1, p.W3[1], s, row0, rows, Cg, sU);
    } else if (t < 21) {    // (3,2e)
        int rel = t - 14, row0 = rel * 24, rows = (rel == 6) ? 21 : 24;
        coefRegion<13, 5, 4, 0>(Us + US3_2, p.W3[2], s, row0, rows, Cg, sU);
    } else if (t < 23) {    // (2,0e) rows 45
        int rel = t - 21, row0 = rel * 24, rows = (rel == 1) ? 21 : 24;
        coefRegion<3, 1, 0, 165>(Us + US2_0, p.W2[0], s, row0, rows, Cg, sU);
    } else if (t < 25) {    // (2,1o)
        int rel = t - 23, row0 = rel * 24, rows = (rel == 1) ? 21 : 24;
        coefRegion<2, 3, 1, 165>(Us + US2_1, p.W2[1], s, row0, rows, Cg, sU);
    } else if (t < 27) {    // (2,2e)
        int rel = t - 25, row0 = rel * 24, rows = (rel == 1) ? 21 : 24;
        coefRegion<3, 5, 4, 165>(Us + US2_2, p.W2[2], s, row0, rows, Cg, sU);
    } else if (t == 27) {   // (1,0e) rows 9, U1 read directly (mul=1 layout matches)
        coefRegion<1, 1, 0, 210>(p.U1[0], p.W1[0], s, 0, 9, Cg, sU);
    } else if (t == 28) {   // (1,1o)
        coefRegion<1, 3, 1, 210>(p.U1[1], p.W1[1], s, 0, 9, Cg, sU);
    } else {                // (1,2e)
        coefRegion<1, 5, 4, 210>(p.U1[2], p.W1[2], s, 0, 9, Cg, sU);
    }
}

// ---------------------------------------------------------------------------
// Kernel 4: evaluation. One block per (species, channel), 256 threads,
// 1 node/thread. Page staged flat into LDS (8 KB, coalesced), then the fully
// unrolled monomial stream reads 2x ds_read_b128 + ds_read_b32 per monomial
// with compile-time offsets. 5 blocks/CU x 4 waves = 20 waves/CU.
// ---------------------------------------------------------------------------
__global__ __launch_bounds__(256, 4) void sc_eval_kernel(const float* __restrict__ nf,
                                                         const int* __restrict__ counts,
                                                         const int* __restrict__ lists,
                                                         const float* __restrict__ Cg,
                                                         float* __restrict__ out) {
    __shared__ __align__(16) float sP[PAGE2];
    const int s = blockIdx.x / C_CH;   // 128 consecutive blocks share a species
    const int c = blockIdx.x % C_CH;
    const float* __restrict__ Cp = Cg + (size_t)(s * C_CH + c) * PAGE2;

    {   // flat coalesced 8 KB stage
        const float4* g = (const float4*)Cp;
        float4* l = (float4*)sP;
        l[threadIdx.x]       = g[threadIdx.x];
        l[threadIdx.x + 256] = g[threadIdx.x + 256];
    }
    __syncthreads();

    const int cnt = counts[s];
    const float4* __restrict__ Cv = (const float4*)sP;
    const float*  __restrict__ Ct = sP + MAIN_F;

    for (int base = 0; base < cnt; base += 256) {
        const int i0 = base + threadIdx.x;
        const int m0 = (i0 < cnt) ? lists[s * N_NODES + i0] : -1;
        const float* xp = nf + ((long)(m0 < 0 ? 0 : m0) * C_CH + c) * 9;
        float x[9];
#pragma unroll
        for (int j = 0; j < 9; ++j) x[j] = xp[j];

        float4 oa = {0, 0, 0, 0}, ob = {0, 0, 0, 0};
        float  o8 = 0.f;

        int n3 = 0, n2 = 0;
#pragma unroll
        for (int a = 0; a < 9; ++a) {
            const float xa = x[a];
            {   // S1 monomial m = 210+a
                const int m = 210 + a;
                oa += Cv[m * 2] * xa; ob += Cv[m * 2 + 1] * xa; o8 += Ct[m] * xa;
            }
#pragma unroll
            for (int b = a; b < 9; ++b) {
                const float xab = xa * x[b];
                {   // S2 monomial m = 165+n2
                    const int m = 165 + n2;
                    oa += Cv[m * 2] * xab; ob += Cv[m * 2 + 1] * xab; o8 += Ct[m] * xab;
                }
#pragma unroll
                for (int j = b; j < 9; ++j) {
                    const float mono = xab * x[j];
                    oa += Cv[n3 * 2] * mono; ob += Cv[n3 * 2 + 1] * mono;
                    o8 += Ct[n3] * mono;
                    ++n3;
                }
                ++n2;
            }
        }

        if (m0 >= 0) {
            float* op = out + ((long)m0 * C_CH + c) * 9;
            op[0] = oa.x; op[1] = oa.y; op[2] = oa.z; op[3] = oa.w;
            op[4] = ob.x; op[5] = ob.y; op[6] = ob.z; op[7] = ob.w;
            op[8] = o8;
        }
    }
}

// ---------------------------------------------------------------------------
// Fallback path (round-0 verified kernel) in case ws_size is too small.
// ---------------------------------------------------------------------------
template <int NAB, int MUL, int IRD, int IOFF>
__device__ inline void buildC(const float* __restrict__ u, const float* __restrict__ w,
                              int s, int c, float* __restrict__ sMain, float* __restrict__ sB) {
    const int tid = threadIdx.x;
    const float* wp = w + (s * MUL) * C_CH + c;
    for (int e = tid; e < NAB * IRD; e += 128) {
        int abj = e / IRD;
        int il  = e - abj * IRD;
        const float* up = u + (abj * MUL) * IRD + il;
        float acc = 0.f;
#pragma unroll
        for (int k = 0; k < MUL; ++k)
            acc += up[k * IRD] * wp[k * C_CH];
        int i = IOFF + il;
        if (i < 8) sMain[abj * 8 + i] = acc;
        else       sB[abj] = acc;
    }
}

__device__ inline float selx(const float x[9], int a) {
    float r = x[0];
    r = (a == 1) ? x[1] : r; r = (a == 2) ? x[2] : r; r = (a == 3) ? x[3] : r;
    r = (a == 4) ? x[4] : r; r = (a == 5) ? x[5] : r; r = (a == 6) ? x[6] : r;
    r = (a == 7) ? x[7] : r; r = (a == 8) ? x[8] : r;
    return r;
}

__global__ __launch_bounds__(128) void sc_kernel(const float* __restrict__ nf,
                                                 const int* __restrict__ counts,
                                                 const int* __restrict__ lists,
                                                 Params p,
                                                 float* __restrict__ out) {
    __shared__ __align__(16) float sC3[729 * 8];
    __shared__ float sC3b[729];
    __shared__ __align__(16) float sC2[81 * 8];
    __shared__ float sC2b[81];
    __shared__ __align__(16) float sC1[9 * 8];
    __shared__ float sC1b[9];

    const int s = blockIdx.x % N_SPEC;
    const int c = blockIdx.x / N_SPEC;
    const int tid = threadIdx.x;

    buildC<729, 10, 1, 0>(p.U3[0], p.W3[0], s, c, sC3, sC3b);
    buildC<729, 11, 3, 1>(p.U3[1], p.W3[1], s, c, sC3, sC3b);
    buildC<729, 13, 5, 4>(p.U3[2], p.W3[2], s, c, sC3, sC3b);
    buildC<81, 3, 1, 0>(p.U2[0], p.W2[0], s, c, sC2, sC2b);
    buildC<81, 2, 3, 1>(p.U2[1], p.W2[1], s, c, sC2, sC2b);
    buildC<81, 3, 5, 4>(p.U2[2], p.W2[2], s, c, sC2, sC2b);
    buildC<9, 1, 1, 0>(p.U1[0], p.W1[0], s, c, sC1, sC1b);
    buildC<9, 1, 3, 1>(p.U1[1], p.W1[1], s, c, sC1, sC1b);
    buildC<9, 1, 5, 4>(p.U1[2], p.W1[2], s, c, sC1, sC1b);
    __syncthreads();

    const int cnt = counts[s];
    const float4* C3v = (const float4*)sC3;
    const float4* C2v = (const float4*)sC2;
    const float4* C1v = (const float4*)sC1;

    for (int base = 0; base < cnt; base += 256) {
        const int i0 = base + tid;
        const int i1 = base + 128 + tid;
        const int m0 = (i0 < cnt) ? lists[s * N_NODES + i0] : -1;
        const int m1 = (i1 < cnt) ? lists[s * N_NODES + i1] : -1;

        const float* x0p = nf + ((long)(m0 < 0 ? 0 : m0) * C_CH + c) * 9;
        const float* x1p = nf + ((long)(m1 < 0 ? 0 : m1) * C_CH + c) * 9;
        float x0[9], x1[9];
#pragma unroll
        for (int j = 0; j < 9; ++j) { x0[j] = x0p[j]; x1[j] = x1p[j]; }

        float4 o0a = {0, 0, 0, 0}, o0b = {0, 0, 0, 0};
        float4 o1a = {0, 0, 0, 0}, o1b = {0, 0, 0, 0};
        float o08 = 0.f, o18 = 0.f;

#pragma unroll 1
        for (int a = 0; a < 9; ++a) {
            const float xa0 = selx(x0, a);
            const float xa1 = selx(x1, a);
            const float4 c1a = C1v[a * 2], c1b = C1v[a * 2 + 1];
            const float  c18 = sC1b[a];
            float4 q0a = c1a, q0b = c1b; float q08 = c18;
            float4 q1a = c1a, q1b = c1b; float q18 = c18;
#pragma unroll
            for (int b = 0; b < 9; ++b) {
                const int ab = a * 9 + b;
                const float4 c2a = C2v[ab * 2], c2b = C2v[ab * 2 + 1];
                const float  c28 = sC2b[ab];
                float4 t0a = c2a, t0b = c2b; float t08 = c28;
                float4 t1a = c2a, t1b = c2b; float t18 = c28;
#pragma unroll
                for (int j = 0; j < 9; ++j) {
                    const int abj = ab * 9 + j;
                    const float4 ca = C3v[abj * 2];
                    const float4 cb = C3v[abj * 2 + 1];
                    const float  c8 = sC3b[abj];
                    t0a += ca * x0[j]; t0b += cb * x0[j]; t08 += c8 * x0[j];
                    t1a += ca * x1[j]; t1b += cb * x1[j]; t18 += c8 * x1[j];
                }
                q0a += t0a * x0[b]; q0b += t0b * x0[b]; q08 += t08 * x0[b];
                q1a += t1a * x1[b]; q1b += t1b * x1[b]; q18 += t18 * x1[b];
            }
            o0a += q0a * xa0; o0b += q0b * xa0; o08 += q08 * xa0;
            o1a += q1a * xa1; o1b += q1b * xa1; o18 += q18 * xa1;
        }

        if (m0 >= 0) {
            float* op = out + ((long)m0 * C_CH + c) * 9;
            op[0] = o0a.x; op[1] = o0a.y; op[2] = o0a.z; op[3] = o0a.w;
            op[4] = o0b.x; op[5] = o0b.y; op[6] = o0b.z; op[7] = o0b.w;
            op[8] = o08;
        }
        if (m1 >= 0) {
            float* op = out + ((long)m1 * C_CH + c) * 9;
            op[0] = o1a.x; op[1] = o1a.y; op[2] = o1a.z; op[3] = o1a.w;
            op[4] = o1b.x; op[5] = o1b.y; op[6] = o1b.z; op[7] = o1b.w;
            op[8] = o18;
        }
    }
}

// ---------------------------------------------------------------------------
extern "C" void kernel_launch(void* const* d_in, const int* in_sizes, int n_in,
                              void* d_out, int out_size, void* d_ws, size_t ws_size,
                              hipStream_t stream) {
    const float* nf   = (const float*)d_in[0];
    const int* index  = (const int*)d_in[1];

    Params p;
    p.U3[0] = (const float*)d_in[2];  p.W3[0] = (const float*)d_in[3];
    p.U3[1] = (const float*)d_in[4];  p.W3[1] = (const float*)d_in[5];
    p.U3[2] = (const float*)d_in[6];  p.W3[2] = (const float*)d_in[7];
    p.U2[0] = (const float*)d_in[8];  p.W2[0] = (const float*)d_in[9];
    p.U2[1] = (const float*)d_in[10]; p.W2[1] = (const float*)d_in[11];
    p.U2[2] = (const float*)d_in[12]; p.W2[2] = (const float*)d_in[13];
    p.U1[0] = (const float*)d_in[14]; p.W1[0] = (const float*)d_in[15];
    p.U1[1] = (const float*)d_in[16]; p.W1[1] = (const float*)d_in[17];
    p.U1[2] = (const float*)d_in[18]; p.W1[2] = (const float*)d_in[19];

    int* counts = (int*)d_ws;        // 16 ints
    int* lists  = (int*)d_ws + 16;   // 10 * 2048 ints, ends at 81,984 B

    bucket_kernel<<<1, 1024, 0, stream>>>(index, counts, lists);

    if (ws_size >= (size_t)CG_OFF_B + CG_BYTES) {
        float* Us = (float*)((char*)d_ws + US_OFF_B);
        float* Cg = (float*)((char*)d_ws + CG_OFF_B);
        usym_kernel<<<(US_TOT + 255) / 256, 256, 0, stream>>>(p, Us);
        coef_kernel<<<N_SPEC * 30, 128, 0, stream>>>(p, Us, Cg);
        sc_eval_kernel<<<N_SPEC * C_CH, 256, 0, stream>>>(nf, counts, lists, Cg,
                                                          (float*)d_out);
    } else {
        sc_kernel<<<N_SPEC * C_CH, 128, 0, stream>>>(nf, counts, lists, p,
                                                     (float*)d_out);
    }
}

// Round 4
// 181.431 us; speedup vs baseline: 3.9829x; 3.9829x over previous
//
#include <hip/hip_runtime.h>

#define N_NODES 2048
#define C_CH    128
#define N_SPEC  10

// --- symmetric-reduced coefficient page per (species, channel) ---------------
// Layout: main[219][8] (monomial-major, i=0..7) | tail[219] (i==8), pad to 2048.
// Monomial order: m=0..164 sorted triples a<=b<=j (lex), 165..209 sorted pairs
// a<=b (lex), 210..218 singles a.
#define PAGE2   2048
#define NMONO   219
#define MAIN_F  1752          // 219*8

// --- symmetrized-U region layout (floats, within d_ws at US_OFF_B) ----------
#define US3_0   0        // 165*10*1 = 1650
#define US3_1   1650     // 165*11*3 = 5445
#define US3_2   7095     // 165*13*5 = 10725
#define US2_0   17820    // 45*3*1   = 135
#define US2_1   17955    // 45*2*3   = 270
#define US2_2   18225    // 45*3*5   = 675
#define US_TOT  18900

#define US_OFF_B  (128 * 1024)
#define CG_OFF_B  (256 * 1024)
#define CG_BYTES  ((size_t)N_SPEC * C_CH * PAGE2 * 4)

// ---------------------------------------------------------------------------
// Kernel 1: bucket nodes by species. Single block; LDS atomics for positions.
// ---------------------------------------------------------------------------
__global__ __launch_bounds__(1024) void bucket_kernel(const int* __restrict__ index,
                                                      int* __restrict__ counts,
                                                      int* __restrict__ lists) {
    __shared__ int sc[N_SPEC];
    const int tid = threadIdx.x;
    if (tid < N_SPEC) sc[tid] = 0;
    __syncthreads();
    for (int n = tid; n < N_NODES; n += blockDim.x) {
        int s = index[n];
        int pos = atomicAdd(&sc[s], 1);
        lists[s * N_NODES + pos] = n;
    }
    __syncthreads();
    if (tid < N_SPEC) counts[tid] = sc[tid];
}

struct Params {
    const float* U3[3]; const float* W3[3];
    const float* U2[3]; const float* W2[3];
    const float* U1[3]; const float* W1[3];
};

// ---------------------------------------------------------------------------
// Kernel 2: symmetrize U over permutation groups of the feature indices.
// (verified rounds 2-3, unchanged)
// ---------------------------------------------------------------------------
__global__ __launch_bounds__(256) void usym_kernel(Params p, float* __restrict__ Us) {
    const int t = blockIdx.x * 256 + threadIdx.x;
    if (t >= US_TOT) return;

    bool is3; int mul, ird, r; const float* u;
    if (t < US3_1)       { is3 = true;  mul = 10; ird = 1; r = t;          u = p.U3[0]; }
    else if (t < US3_2)  { is3 = true;  mul = 11; ird = 3; r = t - US3_1;  u = p.U3[1]; }
    else if (t < US2_0)  { is3 = true;  mul = 13; ird = 5; r = t - US3_2;  u = p.U3[2]; }
    else if (t < US2_1)  { is3 = false; mul = 3;  ird = 1; r = t - US2_0;  u = p.U2[0]; }
    else if (t < US2_2)  { is3 = false; mul = 2;  ird = 3; r = t - US2_1;  u = p.U2[1]; }
    else                 { is3 = false; mul = 3;  ird = 5; r = t - US2_2;  u = p.U2[2]; }

    const int mi  = mul * ird;
    const int n   = r / mi;
    const int rem = r - n * mi;           // k*ird + il

    float acc = 0.f;
    if (is3) {
        int aa = 0, bb = 0, jj = 0, ctr = 0;
        for (int a2 = 0; a2 < 9; ++a2)
            for (int b2 = a2; b2 < 9; ++b2)
                for (int j2 = b2; j2 < 9; ++j2) {
                    if (ctr == n) { aa = a2; bb = b2; jj = j2; }
                    ++ctr;
                }
        int L[6];
        L[0] = (aa * 9 + bb) * 9 + jj; L[1] = (aa * 9 + jj) * 9 + bb;
        L[2] = (bb * 9 + aa) * 9 + jj; L[3] = (bb * 9 + jj) * 9 + aa;
        L[4] = (jj * 9 + aa) * 9 + bb; L[5] = (jj * 9 + bb) * 9 + aa;
        for (int m = 0; m < 6; ++m) {
            bool dup = false;
            for (int mm = 0; mm < m; ++mm) dup = dup || (L[mm] == L[m]);
            if (!dup) acc += u[L[m] * mi + rem];
        }
    } else {
        int aa = 0, bb = 0, ctr = 0;
        for (int a2 = 0; a2 < 9; ++a2)
            for (int b2 = a2; b2 < 9; ++b2) {
                if (ctr == n) { aa = a2; bb = b2; }
                ++ctr;
            }
        acc = u[(aa * 9 + bb) * mi + rem];
        if (aa != bb) acc += u[(bb * 9 + aa) * mi + rem];
    }
    Us[t] = acc;
}

// ---------------------------------------------------------------------------
// Kernel 3: build pages (verified round 3, unchanged). lane = channel; W slice
// in registers; Us chunk staged in LDS, broadcast-read.
// ---------------------------------------------------------------------------
template <int MUL, int IRD, int IOFF, int MOFF>
__device__ inline void coefRegion(const float* __restrict__ src,   // rows*MUL*IRD
                                  const float* __restrict__ W,     // [spec][MUL][C]
                                  int s, int row0, int rows,
                                  float* __restrict__ Cg, float* __restrict__ sU) {
    const int c   = threadIdx.x;
    float wv[MUL];
#pragma unroll
    for (int k = 0; k < MUL; ++k) wv[k] = W[(s * MUL + k) * C_CH + c];

    const int nfl = rows * MUL * IRD;
    const float* sp = src + row0 * MUL * IRD;
    for (int f = c; f < nfl; f += 128) sU[f] = sp[f];
    __syncthreads();

    const size_t pb = (size_t)(s * C_CH + c) * PAGE2;
    for (int rr = 0; rr < rows; ++rr) {
        const int m = MOFF + row0 + rr;
#pragma unroll
        for (int il = 0; il < IRD; ++il) {
            float a = 0.f;
#pragma unroll
            for (int k = 0; k < MUL; ++k)
                a += sU[(rr * MUL + k) * IRD + il] * wv[k];
            const int i = IOFF + il;
            Cg[pb + (i < 8 ? m * 8 + i : MAIN_F + m)] = a;
        }
    }
}

__global__ __launch_bounds__(128) void coef_kernel(Params p, const float* __restrict__ Us,
                                                   float* __restrict__ Cg) {
    __shared__ float sU[1560];   // max chunk: 24 rows * 13 * 5
    const int s = blockIdx.x / 30;
    const int t = blockIdx.x % 30;

    if (t < 7) {
        int rel = t, row0 = rel * 24, rows = (rel == 6) ? 21 : 24;
        coefRegion<10, 1, 0, 0>(Us + US3_0, p.W3[0], s, row0, rows, Cg, sU);
    } else if (t < 14) {
        int rel = t - 7, row0 = rel * 24, rows = (rel == 6) ? 21 : 24;
        coefRegion<11, 3, 1, 0>(Us + US3_1, p.W3[1], s, row0, rows, Cg, sU);
    } else if (t < 21) {
        int rel = t - 14, row0 = rel * 24, rows = (rel == 6) ? 21 : 24;
        coefRegion<13, 5, 4, 0>(Us + US3_2, p.W3[2], s, row0, rows, Cg, sU);
    } else if (t < 23) {
        int rel = t - 21, row0 = rel * 24, rows = (rel == 1) ? 21 : 24;
        coefRegion<3, 1, 0, 165>(Us + US2_0, p.W2[0], s, row0, rows, Cg, sU);
    } else if (t < 25) {
        int rel = t - 23, row0 = rel * 24, rows = (rel == 1) ? 21 : 24;
        coefRegion<2, 3, 1, 165>(Us + US2_1, p.W2[1], s, row0, rows, Cg, sU);
    } else if (t < 27) {
        int rel = t - 25, row0 = rel * 24, rows = (rel == 1) ? 21 : 24;
        coefRegion<3, 5, 4, 165>(Us + US2_2, p.W2[2], s, row0, rows, Cg, sU);
    } else if (t == 27) {
        coefRegion<1, 1, 0, 210>(p.U1[0], p.W1[0], s, 0, 9, Cg, sU);
    } else if (t == 28) {
        coefRegion<1, 3, 1, 210>(p.U1[1], p.W1[1], s, 0, 9, Cg, sU);
    } else {
        coefRegion<1, 5, 4, 210>(p.U1[2], p.W1[2], s, 0, 9, Cg, sU);
    }
}

// dynamic index into a register array without scratch: cndmask chain (a is 0..8,
// wave-uniform selector -> s_cmp + v_cndmask, no LDS, no scratch)
__device__ inline float selx(const float x[9], int a) {
    float r = x[0];
    r = (a == 1) ? x[1] : r; r = (a == 2) ? x[2] : r; r = (a == 3) ? x[3] : r;
    r = (a == 4) ? x[4] : r; r = (a == 5) ? x[5] : r; r = (a == 6) ? x[6] : r;
    r = (a == 7) ? x[7] : r; r = (a == 8) ? x[8] : r;
    return r;
}

// ---------------------------------------------------------------------------
// Kernel 4: evaluation. One block per (species, channel), 128 threads,
// 2 nodes/thread. Page staged flat into LDS (8 KB, coalesced). All monomial
// loops ROLLED (#pragma unroll 1) with running coefficient pointers --
// small I$ body, ~80 VGPR live set, no scheduler ds_read hoisting blow-up
// (round 3's full unroll spilled 3 KB/thread to scratch: 1.7 GB HBM thrash).
// ---------------------------------------------------------------------------
__global__ __launch_bounds__(128) void sc_eval_kernel(const float* __restrict__ nf,
                                                      const int* __restrict__ counts,
                                                      const int* __restrict__ lists,
                                                      const float* __restrict__ Cg,
                                                      float* __restrict__ out) {
    __shared__ __align__(16) float sP[PAGE2];
    const int s = blockIdx.x / C_CH;   // 128 consecutive blocks share a species
    const int c = blockIdx.x % C_CH;
    const float* __restrict__ Cp = Cg + (size_t)(s * C_CH + c) * PAGE2;

    {   // flat coalesced 8 KB stage: 128 threads x 4 float4
        const float4* g = (const float4*)Cp;
        float4* l = (float4*)sP;
#pragma unroll
        for (int q = 0; q < 4; ++q) l[threadIdx.x + 128 * q] = g[threadIdx.x + 128 * q];
    }
    __syncthreads();

    const int cnt = counts[s];
    const float4* __restrict__ Cv = (const float4*)sP;
    const float*  __restrict__ Ct = sP + MAIN_F;

    for (int base = 0; base < cnt; base += 256) {
        const int i0 = base + threadIdx.x;
        const int i1 = base + 128 + threadIdx.x;
        const int m0 = (i0 < cnt) ? lists[s * N_NODES + i0] : -1;
        const int m1 = (i1 < cnt) ? lists[s * N_NODES + i1] : -1;

        const float* x0p = nf + ((long)(m0 < 0 ? 0 : m0) * C_CH + c) * 9;
        const float* x1p = nf + ((long)(m1 < 0 ? 0 : m1) * C_CH + c) * 9;
        float x0[9], x1[9];
#pragma unroll
        for (int j = 0; j < 9; ++j) { x0[j] = x0p[j]; x1[j] = x1p[j]; }

        float4 o0a = {0, 0, 0, 0}, o0b = {0, 0, 0, 0};
        float4 o1a = {0, 0, 0, 0}, o1b = {0, 0, 0, 0};
        float o08 = 0.f, o18 = 0.f;

        const float4* p3 = Cv;            // triples main, advances 2/monomial
        const float*  t3 = Ct;            // triples tail
        const float4* p2 = Cv + 165 * 2;  // pairs main
        const float*  t2 = Ct + 165;      // pairs tail

#pragma unroll 1
        for (int a = 0; a < 9; ++a) {
            const float xa0 = selx(x0, a);
            const float xa1 = selx(x1, a);
            {   // S1 monomial m = 210+a
                const float4 ca = Cv[(210 + a) * 2], cb = Cv[(210 + a) * 2 + 1];
                const float  c8 = Ct[210 + a];
                o0a += ca * xa0; o0b += cb * xa0; o08 += c8 * xa0;
                o1a += ca * xa1; o1b += cb * xa1; o18 += c8 * xa1;
            }
#pragma unroll 1
            for (int b = a; b < 9; ++b) {
                const float xb0 = selx(x0, b) * xa0;
                const float xb1 = selx(x1, b) * xa1;
                {   // S2 monomial
                    const float4 ca = p2[0], cb = p2[1];
                    const float  c8 = *t2;
                    o0a += ca * xb0; o0b += cb * xb0; o08 += c8 * xb0;
                    o1a += ca * xb1; o1b += cb * xb1; o18 += c8 * xb1;
                    p2 += 2; ++t2;
                }
#pragma unroll 1
                for (int j = b; j < 9; ++j) {   // S3 monomials
                    const float mn0 = selx(x0, j) * xb0;
                    const float mn1 = selx(x1, j) * xb1;
                    const float4 ca = p3[0], cb = p3[1];
                    const float  c8 = *t3;
                    o0a += ca * mn0; o0b += cb * mn0; o08 += c8 * mn0;
                    o1a += ca * mn1; o1b += cb * mn1; o18 += c8 * mn1;
                    p3 += 2; ++t3;
                }
            }
        }

        if (m0 >= 0) {
            float* op = out + ((long)m0 * C_CH + c) * 9;
            op[0] = o0a.x; op[1] = o0a.y; op[2] = o0a.z; op[3] = o0a.w;
            op[4] = o0b.x; op[5] = o0b.y; op[6] = o0b.z; op[7] = o0b.w;
            op[8] = o08;
        }
        if (m1 >= 0) {
            float* op = out + ((long)m1 * C_CH + c) * 9;
            op[0] = o1a.x; op[1] = o1a.y; op[2] = o1a.z; op[3] = o1a.w;
            op[4] = o1b.x; op[5] = o1b.y; op[6] = o1b.z; op[7] = o1b.w;
            op[8] = o18;
        }
    }
}

// ---------------------------------------------------------------------------
// Fallback path (round-0 verified kernel) in case ws_size is too small.
// ---------------------------------------------------------------------------
template <int NAB, int MUL, int IRD, int IOFF>
__device__ inline void buildC(const float* __restrict__ u, const float* __restrict__ w,
                              int s, int c, float* __restrict__ sMain, float* __restrict__ sB) {
    const int tid = threadIdx.x;
    const float* wp = w + (s * MUL) * C_CH + c;
    for (int e = tid; e < NAB * IRD; e += 128) {
        int abj = e / IRD;
        int il  = e - abj * IRD;
        const float* up = u + (abj * MUL) * IRD + il;
        float acc = 0.f;
#pragma unroll
        for (int k = 0; k < MUL; ++k)
            acc += up[k * IRD] * wp[k * C_CH];
        int i = IOFF + il;
        if (i < 8) sMain[abj * 8 + i] = acc;
        else       sB[abj] = acc;
    }
}

__global__ __launch_bounds__(128) void sc_kernel(const float* __restrict__ nf,
                                                 const int* __restrict__ counts,
                                                 const int* __restrict__ lists,
                                                 Params p,
                                                 float* __restrict__ out) {
    __shared__ __align__(16) float sC3[729 * 8];
    __shared__ float sC3b[729];
    __shared__ __align__(16) float sC2[81 * 8];
    __shared__ float sC2b[81];
    __shared__ __align__(16) float sC1[9 * 8];
    __shared__ float sC1b[9];

    const int s = blockIdx.x % N_SPEC;
    const int c = blockIdx.x / N_SPEC;
    const int tid = threadIdx.x;

    buildC<729, 10, 1, 0>(p.U3[0], p.W3[0], s, c, sC3, sC3b);
    buildC<729, 11, 3, 1>(p.U3[1], p.W3[1], s, c, sC3, sC3b);
    buildC<729, 13, 5, 4>(p.U3[2], p.W3[2], s, c, sC3, sC3b);
    buildC<81, 3, 1, 0>(p.U2[0], p.W2[0], s, c, sC2, sC2b);
    buildC<81, 2, 3, 1>(p.U2[1], p.W2[1], s, c, sC2, sC2b);
    buildC<81, 3, 5, 4>(p.U2[2], p.W2[2], s, c, sC2, sC2b);
    buildC<9, 1, 1, 0>(p.U1[0], p.W1[0], s, c, sC1, sC1b);
    buildC<9, 1, 3, 1>(p.U1[1], p.W1[1], s, c, sC1, sC1b);
    buildC<9, 1, 5, 4>(p.U1[2], p.W1[2], s, c, sC1, sC1b);
    __syncthreads();

    const int cnt = counts[s];
    const float4* C3v = (const float4*)sC3;
    const float4* C2v = (const float4*)sC2;
    const float4* C1v = (const float4*)sC1;

    for (int base = 0; base < cnt; base += 256) {
        const int i0 = base + tid;
        const int i1 = base + 128 + tid;
        const int m0 = (i0 < cnt) ? lists[s * N_NODES + i0] : -1;
        const int m1 = (i1 < cnt) ? lists[s * N_NODES + i1] : -1;

        const float* x0p = nf + ((long)(m0 < 0 ? 0 : m0) * C_CH + c) * 9;
        const float* x1p = nf + ((long)(m1 < 0 ? 0 : m1) * C_CH + c) * 9;
        float x0[9], x1[9];
#pragma unroll
        for (int j = 0; j < 9; ++j) { x0[j] = x0p[j]; x1[j] = x1p[j]; }

        float4 o0a = {0, 0, 0, 0}, o0b = {0, 0, 0, 0};
        float4 o1a = {0, 0, 0, 0}, o1b = {0, 0, 0, 0};
        float o08 = 0.f, o18 = 0.f;

#pragma unroll 1
        for (int a = 0; a < 9; ++a) {
            const float xa0 = selx(x0, a);
            const float xa1 = selx(x1, a);
            const float4 c1a = C1v[a * 2], c1b = C1v[a * 2 + 1];
            const float  c18 = sC1b[a];
            float4 q0a = c1a, q0b = c1b; float q08 = c18;
            float4 q1a = c1a, q1b = c1b; float q18 = c18;
#pragma unroll
            for (int b = 0; b < 9; ++b) {
                const int ab = a * 9 + b;
                const float4 c2a = C2v[ab * 2], c2b = C2v[ab * 2 + 1];
                const float  c28 = sC2b[ab];
                float4 t0a = c2a, t0b = c2b; float t08 = c28;
                float4 t1a = c2a, t1b = c2b; float t18 = c28;
#pragma unroll
                for (int j = 0; j < 9; ++j) {
                    const int abj = ab * 9 + j;
                    const float4 ca = C3v[abj * 2];
                    const float4 cb = C3v[abj * 2 + 1];
                    const float  c8 = sC3b[abj];
                    t0a += ca * x0[j]; t0b += cb * x0[j]; t08 += c8 * x0[j];
                    t1a += ca * x1[j]; t1b += cb * x1[j]; t18 += c8 * x1[j];
                }
                q0a += t0a * x0[b]; q0b += t0b * x0[b]; q08 += t08 * x0[b];
                q1a += t1a * x1[b]; q1b += t1b * x1[b]; q18 += t18 * x1[b];
            }
            o0a += q0a * xa0; o0b += q0b * xa0; o08 += q08 * xa0;
            o1a += q1a * xa1; o1b += q1b * xa1; o18 += q18 * xa1;
        }

        if (m0 >= 0) {
            float* op = out + ((long)m0 * C_CH + c) * 9;
            op[0] = o0a.x; op[1] = o0a.y; op[2] = o0a.z; op[3] = o0a.w;
            op[4] = o0b.x; op[5] = o0b.y; op[6] = o0b.z; op[7] = o0b.w;
            op[8] = o08;
        }
        if (m1 >= 0) {
            float* op = out + ((long)m1 * C_CH + c) * 9;
            op[0] = o1a.x; op[1] = o1a.y; op[2] = o1a.z; op[3] = o1a.w;
            op[4] = o1b.x; op[5] = o1b.y; op[6] = o1b.z; op[7] = o1b.w;
            op[8] = o18;
        }
    }
}

// ---------------------------------------------------------------------------
extern "C" void kernel_launch(void* const* d_in, const int* in_sizes, int n_in,
                              void* d_out, int out_size, void* d_ws, size_t ws_size,
                              hipStream_t stream) {
    const float* nf   = (const float*)d_in[0];
    const int* index  = (const int*)d_in[1];

    Params p;
    p.U3[0] = (const float*)d_in[2];  p.W3[0] = (const float*)d_in[3];
    p.U3[1] = (const float*)d_in[4];  p.W3[1] = (const float*)d_in[5];
    p.U3[2] = (const float*)d_in[6];  p.W3[2] = (const float*)d_in[7];
    p.U2[0] = (const float*)d_in[8];  p.W2[0] = (const float*)d_in[9];
    p.U2[1] = (const float*)d_in[10]; p.W2[1] = (const float*)d_in[11];
    p.U2[2] = (const float*)d_in[12]; p.W2[2] = (const float*)d_in[13];
    p.U1[0] = (const float*)d_in[14]; p.W1[0] = (const float*)d_in[15];
    p.U1[1] = (const float*)d_in[16]; p.W1[1] = (const float*)d_in[17];
    p.U1[2] = (const float*)d_in[18]; p.W1[2] = (const float*)d_in[19];

    int* counts = (int*)d_ws;        // 16 ints
    int* lists  = (int*)d_ws + 16;   // 10 * 2048 ints, ends at 81,984 B

    bucket_kernel<<<1, 1024, 0, stream>>>(index, counts, lists);

    if (ws_size >= (size_t)CG_OFF_B + CG_BYTES) {
        float* Us = (float*)((char*)d_ws + US_OFF_B);
        float* Cg = (float*)((char*)d_ws + CG_OFF_B);
        usym_kernel<<<(US_TOT + 255) / 256, 256, 0, stream>>>(p, Us);
        coef_kernel<<<N_SPEC * 30, 128, 0, stream>>>(p, Us, Cg);
        sc_eval_kernel<<<N_SPEC * C_CH, 128, 0, stream>>>(nf, counts, lists, Cg,
                                                          (float*)d_out);
    } else {
        sc_kernel<<<N_SPEC * C_CH, 128, 0, stream>>>(nf, counts, lists, p,
                                                     (float*)d_out);
    }
}